// Round 2
// baseline (273.836 us; speedup 1.0000x reference)
//
#include <hip/hip_runtime.h>
#include <hip/hip_bf16.h>

// QuantizedLinear: q = clip(round(lin/s)), s = max|lin|/127,
// lin = (x_q - x_zp) @ w_q^T + round(fp_bias / (w_scale*x_scale))
// Exact-integer path: x8 = x_q-128 (int8), w8 = w_q (int8),
// lin = x8@w8^T + (128 - x_zp[b])*rowsum(w) + qbias   (all int32, exact)
//
// GEMM structure (this round): 256x256 tile, 512 threads (8 waves, 2Mx4N),
// BK=64 bytes, 4-deep LDS ring (4 x 32KB), counted vmcnt(8) pipeline (T3+T4),
// XOR-swizzled LDS (T2, conflict-free verified r1), setprio (T5), XCD swizzle (T1).

typedef int i32x4 __attribute__((ext_vector_type(4)));

#define AS1 __attribute__((address_space(1)))
#define AS3 __attribute__((address_space(3)))

__device__ __forceinline__ void async16(const void* g, void* lds) {
    __builtin_amdgcn_global_load_lds((const AS1 void*)g, (AS3 void*)lds, 16, 0, 0);
}

// ---- pass 1a: x8[i] = (int8)(x_q[i] - 128); also zero the global max ----
__global__ void conv_x_kernel(const float4* __restrict__ xq, int* __restrict__ x8,
                              int* gmax, int n4) {
    int i = blockIdx.x * 256 + threadIdx.x;
    if (i == 0) *gmax = 0;
    if (i >= n4) return;
    float4 v = xq[i];
    int b0 = ((int)v.x - 128) & 255;
    int b1 = ((int)v.y - 128) & 255;
    int b2 = ((int)v.z - 128) & 255;
    int b3 = ((int)v.w - 128) & 255;
    x8[i] = b0 | (b1 << 8) | (b2 << 16) | (b3 << 24);
}

// ---- pass 1b: w8 = (int8)w_q; rowsum[n] = sum_k w_q[n][k] ----
__global__ void conv_w_kernel(const float* __restrict__ wq, int* __restrict__ w8,
                              int* __restrict__ rowsum, int K) {
    int row = blockIdx.x;
    int t = threadIdx.x;
    const float4* src = (const float4*)(wq + (size_t)row * K);
    int* dst = w8 + (size_t)row * (K >> 2);
    int sum = 0;
    int passes = K >> 10;  // 256 threads * 4 elements
    for (int p = 0; p < passes; ++p) {
        float4 v = src[p * 256 + t];
        int b0 = (int)v.x, b1 = (int)v.y, b2 = (int)v.z, b3 = (int)v.w;
        sum += b0 + b1 + b2 + b3;
        dst[p * 256 + t] = (b0 & 255) | ((b1 & 255) << 8) | ((b2 & 255) << 16) | ((b3 & 255) << 24);
    }
    #pragma unroll
    for (int m = 32; m; m >>= 1) sum += __shfl_xor(sum, m, 64);
    __shared__ int wsum[4];
    if ((t & 63) == 0) wsum[t >> 6] = sum;
    __syncthreads();
    if (t == 0) rowsum[row] = wsum[0] + wsum[1] + wsum[2] + wsum[3];
}

// ---- pass 2: int8 GEMM, 256x256 tile, 4-deep counted-vmcnt pipeline ----
__global__ __launch_bounds__(512, 2) void gemm_i8_kernel(
    const char* __restrict__ x8, const char* __restrict__ w8,
    const int* __restrict__ w_rowsum,
    const float* __restrict__ x_scale, const float* __restrict__ x_zp,
    const float* __restrict__ fp_bias, const float* __restrict__ w_scale_p,
    int* __restrict__ lin_out, int* gmax, int N, int K) {
    // ring of 4 K-tile buffers; each: A [256 rows][64B] then B [256 rows][64B]
    __shared__ __align__(16) char lds[4][32768];
    __shared__ int s_bmax;

    const int t = threadIdx.x;
    const int w = t >> 6, l = t & 63;
    if (t == 0) s_bmax = 0;

    // T1: XCD-aware block swizzle (nwg = 512, divisible by 8)
    const int nwg = gridDim.x;
    const int bid = blockIdx.x;
    int swz = bid;
    if ((nwg & 7) == 0) { const int cpx = nwg >> 3; swz = (bid & 7) * cpx + (bid >> 3); }
    const int ntn = N >> 8;            // N / 256
    const int tm = swz / ntn, tn = swz % ntn;

    const int nt = K >> 6;             // number of 64B K-tiles

    // ---- staging addresses (gload_lds: LDS dst lane-linear, source pre-swizzled) ----
    // chunk (w*2+q) covers rows chunk*16 .. +15; lane l -> row chunk*16 + (l>>2), slot l&3
    const int srow = (w << 5) + (l >> 2);              // rows for q=0; q=1 adds 16
    const int phys = (l & 3) ^ ((l >> 3) & 3);         // source slot swizzle (matches read)
    const char* pA0 = x8 + (size_t)(tm * 256 + srow) * K + phys * 16;
    const char* pA1 = pA0 + (size_t)16 * K;
    const char* pB0 = w8 + (size_t)(tn * 256 + srow) * K + phys * 16;
    const char* pB1 = pB0 + (size_t)16 * K;
    const int dA0 = (w << 11) + (l << 4);              // (w*2)*1024 + l*16
    const int dA1 = dA0 + 1024;

    // ---- fragment read offsets (swizzled, 2-way max -> conflict-free) ----
    const int lane_lo = l & 15, lane_hi = l >> 4;
    const int wm = w >> 2, wn = w & 3;                 // 2 x 4 wave grid
    const int sl = (lane_hi ^ ((lane_lo >> 1) & 3)) << 4;
    const int abase = (wm * 128 + lane_lo) * 64 + sl;          // + m*1024
    const int bbase = 16384 + (wn * 64 + lane_lo) * 64 + sl;   // + n*1024

    i32x4 acc[8][4] = {};

    // prologue: stage K-tiles 0..2 into bufs 0..2 (12 loads/thread in flight)
    #pragma unroll
    for (int g = 0; g < 3; ++g) {
        char* buf = lds[g];
        const size_t koff = (size_t)g * 64;
        async16(pA0 + koff, buf + dA0);
        async16(pA1 + koff, buf + dA1);
        async16(pB0 + koff, buf + 16384 + dA0);
        async16(pB1 + koff, buf + 16384 + dA1);
    }

    for (int j = 0; j < nt; ++j) {
        // all LDS reads of iter j-1 complete before the barrier (airtight ordering)
        asm volatile("s_waitcnt lgkmcnt(0)" ::: "memory");
        // retire exactly stage-group j; keep groups j+1, j+2 (8 loads) in flight
        if (j + 2 < nt)       asm volatile("s_waitcnt vmcnt(8)" ::: "memory");
        else if (j + 2 == nt) asm volatile("s_waitcnt vmcnt(4)" ::: "memory");
        else                  asm volatile("s_waitcnt vmcnt(0)" ::: "memory");
        __builtin_amdgcn_s_barrier();
        asm volatile("" ::: "memory");
        // stage K-tile j+3 into the buffer freed at the end of iter j-1
        if (j + 3 < nt) {
            char* buf = lds[(j + 3) & 3];
            const size_t koff = (size_t)(j + 3) * 64;
            async16(pA0 + koff, buf + dA0);
            async16(pA1 + koff, buf + dA1);
            async16(pB0 + koff, buf + 16384 + dA0);
            async16(pB1 + koff, buf + 16384 + dA1);
        }
        const char* buf = lds[j & 3];
        i32x4 af[8], bf[4];
        #pragma unroll
        for (int m = 0; m < 8; ++m) af[m] = *(const i32x4*)(buf + abase + m * 1024);
        #pragma unroll
        for (int n = 0; n < 4; ++n) bf[n] = *(const i32x4*)(buf + bbase + n * 1024);
        __builtin_amdgcn_s_setprio(1);
        #pragma unroll
        for (int m = 0; m < 8; ++m)
            #pragma unroll
            for (int n = 0; n < 4; ++n)
                acc[m][n] = __builtin_amdgcn_mfma_i32_16x16x64_i8(af[m], bf[n], acc[m][n], 0, 0, 0);
        __builtin_amdgcn_s_setprio(0);
    }

    // ---- epilogue: lin = acc + z*rowsum + round(fp_bias/(ws*xs)); track max|lin| ----
    const float ws = *w_scale_p;
    const int rowg0 = tm * 256 + wm * 128 + lane_hi * 4;   // + m*16 + r
    const int colg0 = tn * 256 + wn * 64 + lane_lo;        // + n*16
    float fb[4]; int wrs[4];
    #pragma unroll
    for (int n = 0; n < 4; ++n) {
        fb[n] = fp_bias[colg0 + n * 16];
        wrs[n] = w_rowsum[colg0 + n * 16];
    }
    int lmax = 0;
    #pragma unroll
    for (int m = 0; m < 8; ++m) {
        #pragma unroll
        for (int r = 0; r < 4; ++r) {
            const int row = rowg0 + m * 16 + r;
            const float xs = x_scale[row];
            const int zz = 128 - (int)x_zp[row];
            const float d = ws * xs;
            int* orow = lin_out + (size_t)row * N + colg0;
            #pragma unroll
            for (int n = 0; n < 4; ++n) {
                const int qb = (int)rintf(fb[n] / d);
                const int lin = acc[m][n][r] + zz * wrs[n] + qb;
                const int a = lin < 0 ? -lin : lin;
                lmax = a > lmax ? a : lmax;
                orow[n * 16] = lin;
            }
        }
    }
    atomicMax(&s_bmax, lmax);
    __syncthreads();
    if (t == 0) atomicMax(gmax, s_bmax);
}

// ---- pass 3: requantize in place (int32 lin -> float q) ----
__global__ void requant_kernel(float4* qout, const int4* lin, const int* gmax, int n4) {
    int i = blockIdx.x * 256 + threadIdx.x;
    if (i >= n4) return;
    float s = (float)(*gmax) / 127.0f;
    int4 v = lin[i];
    float4 o;
    o.x = fminf(127.0f, fmaxf(-127.0f, rintf((float)v.x / s)));
    o.y = fminf(127.0f, fmaxf(-127.0f, rintf((float)v.y / s)));
    o.z = fminf(127.0f, fmaxf(-127.0f, rintf((float)v.z / s)));
    o.w = fminf(127.0f, fmaxf(-127.0f, rintf((float)v.w / s)));
    qout[i] = o;
}

// ---- pass 4: out_scale[b] = s * x_scale[b] * w_scale; zero_point = 0 ----
__global__ void scale_kernel(float* __restrict__ out_scale, float* __restrict__ out_zp,
                             const float* __restrict__ x_scale,
                             const float* __restrict__ w_scale_p,
                             const int* gmax, int B) {
    int i = blockIdx.x * 256 + threadIdx.x;
    if (i >= B) return;
    float s = (float)(*gmax) / 127.0f;
    out_scale[i] = s * x_scale[i] * w_scale_p[0];
    out_zp[i] = 0.0f;
}

extern "C" void kernel_launch(void* const* d_in, const int* in_sizes, int n_in,
                              void* d_out, int out_size, void* d_ws, size_t ws_size,
                              hipStream_t stream) {
    const float* x_q     = (const float*)d_in[0];
    const float* x_scale = (const float*)d_in[1];
    const float* x_zp    = (const float*)d_in[2];
    const float* w_q     = (const float*)d_in[3];
    const float* w_scale = (const float*)d_in[4];
    const float* fp_bias = (const float*)d_in[5];

    const int B   = in_sizes[1];           // 8192
    const int IN  = in_sizes[0] / B;       // 4096
    const int OUT = in_sizes[5];           // 4096

    float* q         = (float*)d_out;
    float* out_scale = q + (size_t)B * OUT;
    float* out_zp    = out_scale + B;

    // workspace layout
    char* ws    = (char*)d_ws;
    int* gmax   = (int*)ws;
    char* x8    = ws + 64;
    char* w8    = x8 + (size_t)B * IN;
    int* rowsum = (int*)(w8 + (size_t)OUT * IN);
    size_t needed = 64 + (size_t)B * IN + (size_t)OUT * IN + (size_t)OUT * 4;
    if (ws_size < needed) return;  // would corrupt; fail loudly with zero output

    int n4x = (B * IN) >> 2;
    conv_x_kernel<<<(n4x + 255) / 256, 256, 0, stream>>>((const float4*)x_q, (int*)x8, gmax, n4x);
    conv_w_kernel<<<OUT, 256, 0, stream>>>(w_q, (int*)w8, rowsum, IN);

    int nblocks = (B / 256) * (OUT / 256);   // 512
    gemm_i8_kernel<<<nblocks, 512, 0, stream>>>(x8, w8, rowsum, x_scale, x_zp, fp_bias,
                                                w_scale, (int*)q, gmax, OUT, IN);

    int n4q = (B * OUT) >> 2;
    requant_kernel<<<(n4q + 255) / 256, 256, 0, stream>>>((float4*)q, (const int4*)q, gmax, n4q);
    scale_kernel<<<(B + 255) / 256, 256, 0, stream>>>(out_scale, out_zp, x_scale, w_scale, gmax, B);
}

// Round 3
// 257.406 us; speedup vs baseline: 1.0638x; 1.0638x over previous
//
#include <hip/hip_runtime.h>
#include <hip/hip_bf16.h>

// QuantizedLinear: q = clip(round(lin/s)), s = max|lin|/127,
// lin = (x_q - x_zp) @ w_q^T + round(fp_bias / (w_scale*x_scale))
// Exact-integer path: x8 = x_q-128 (int8), w8 = w_q (int8),
// lin = x8@w8^T + (128 - x_zp[b])*rowsum(w) + qbias   (all int32, exact)
//
// GEMM (r3): 256x256 tile, 512 thr (8 waves 2Mx4N), BK=128B, 2-buf LDS 128KB,
// 4 fine phases per K-tile (16 MFMA each), counted waits, 8-slot XOR swizzle,
// setprio around MFMA, XCD swizzle.

typedef int i32x4 __attribute__((ext_vector_type(4)));

#define AS1 __attribute__((address_space(1)))
#define AS3 __attribute__((address_space(3)))

__device__ __forceinline__ void async16(const void* g, void* lds) {
    __builtin_amdgcn_global_load_lds((const AS1 void*)g, (AS3 void*)lds, 16, 0, 0);
}

// ---- pass 1a: x8[i] = (int8)(x_q[i] - 128); also zero the global max ----
__global__ void conv_x_kernel(const float4* __restrict__ xq, int* __restrict__ x8,
                              int* gmax, int n4) {
    int i = blockIdx.x * 256 + threadIdx.x;
    if (i == 0) *gmax = 0;
    if (i >= n4) return;
    float4 v = xq[i];
    int b0 = ((int)v.x - 128) & 255;
    int b1 = ((int)v.y - 128) & 255;
    int b2 = ((int)v.z - 128) & 255;
    int b3 = ((int)v.w - 128) & 255;
    x8[i] = b0 | (b1 << 8) | (b2 << 16) | (b3 << 24);
}

// ---- pass 1b: w8 = (int8)w_q; rowsum[n] = sum_k w_q[n][k] ----
__global__ void conv_w_kernel(const float* __restrict__ wq, int* __restrict__ w8,
                              int* __restrict__ rowsum, int K) {
    int row = blockIdx.x;
    int t = threadIdx.x;
    const float4* src = (const float4*)(wq + (size_t)row * K);
    int* dst = w8 + (size_t)row * (K >> 2);
    int sum = 0;
    int passes = K >> 10;  // 256 threads * 4 elements
    for (int p = 0; p < passes; ++p) {
        float4 v = src[p * 256 + t];
        int b0 = (int)v.x, b1 = (int)v.y, b2 = (int)v.z, b3 = (int)v.w;
        sum += b0 + b1 + b2 + b3;
        dst[p * 256 + t] = (b0 & 255) | ((b1 & 255) << 8) | ((b2 & 255) << 16) | ((b3 & 255) << 24);
    }
    #pragma unroll
    for (int m = 32; m; m >>= 1) sum += __shfl_xor(sum, m, 64);
    __shared__ int wsum[4];
    if ((t & 63) == 0) wsum[t >> 6] = sum;
    __syncthreads();
    if (t == 0) rowsum[row] = wsum[0] + wsum[1] + wsum[2] + wsum[3];
}

// ---- pass 2: int8 GEMM, 256x256 tile, 4-phase interleaved pipeline ----
__global__ __launch_bounds__(512, 2) void gemm_i8_kernel(
    const char* __restrict__ x8, const char* __restrict__ w8,
    const int* __restrict__ w_rowsum,
    const float* __restrict__ x_scale, const float* __restrict__ x_zp,
    const float* __restrict__ fp_bias, const float* __restrict__ w_scale_p,
    int* __restrict__ lin_out, int* gmax, int N, int K) {
    // 2 buffers; each: A 256 rows x 128B (32KB) then B 256 rows x 128B (32KB)
    __shared__ __align__(16) char lds[2][65536];
    __shared__ int s_bmax;

    const int t = threadIdx.x;
    const int w = t >> 6, l = t & 63;
    if (t == 0) s_bmax = 0;

    // T1: XCD-aware block swizzle (nwg = 512, divisible by 8)
    const int nwg = gridDim.x;
    const int bid = blockIdx.x;
    int swz = bid;
    if ((nwg & 7) == 0) { const int cpx = nwg >> 3; swz = (bid & 7) * cpx + (bid >> 3); }
    const int ntn = N >> 8;            // N / 256
    const int tm = swz / ntn, tn = swz % ntn;

    const int nt = K >> 7;             // K-tiles of 128 bytes

    // ---- staging (gload_lds dst is lane-linear; source slot pre-swizzled) ----
    // thread t handles row (i*64 + t>>3), physical slot t&7; logical slot = phys ^ (row&7)
    const int row_t = t >> 3;                         // 0..63
    const int g_t = (t & 7) ^ (row_t & 7);            // pre-swizzled source slot
    const char* gA = x8 + (size_t)(tm * 256 + row_t) * K + g_t * 16;  // + i*64*K + j*128
    const char* gB = w8 + (size_t)(tn * 256 + row_t) * K + g_t * 16;
    const int dst_t = t * 16;                         // + i*8192 (+32768 for B)

    // ---- fragment read offsets ----
    // af[m][kk]: row = wm*128 + m*16 + lane_lo, logical slot kk*4+lane_hi,
    // phys = (kk*4+lane_hi) ^ (lane_lo&7)  (row&7 == lane_lo&7)
    const int lane_lo = l & 15, lane_hi = l >> 4;
    const int wm = w >> 2, wn = w & 3;                // 2 x 4 wave grid
    const int swz0 = ((lane_hi) ^ (lane_lo & 7)) << 4;
    const int swz1 = ((4 + lane_hi) ^ (lane_lo & 7)) << 4;
    const int abase = (wm * 128 + lane_lo) * 128;             // + m*2048
    const int bbase = 32768 + (wn * 64 + lane_lo) * 128;      // + n*2048

    i32x4 acc[8][4] = {};

    // prologue: stage K-tile 0 into buf 0, drain, rendezvous
    #pragma unroll
    for (int i = 0; i < 4; ++i) {
        async16(gA + (size_t)(i * 64) * K, lds[0] + i * 8192 + dst_t);
        async16(gB + (size_t)(i * 64) * K, lds[0] + 32768 + i * 8192 + dst_t);
    }
    asm volatile("s_waitcnt vmcnt(0)" ::: "memory");
    __builtin_amdgcn_s_barrier();

    for (int j = 0; j < nt; ++j) {
        const char* buf = lds[j & 1];
        char* nbuf = lds[(j + 1) & 1];
        const size_t koff = (size_t)(j + 1) << 7;
        const bool more = (j + 1) < nt;
        i32x4 bf[4][2];

        #pragma unroll
        for (int p = 0; p < 4; ++p) {
            // --- mem region: ds_read this phase's fragments ---
            if (p == 0) {
                #pragma unroll
                for (int n = 0; n < 4; ++n) {
                    bf[n][0] = *(const i32x4*)(buf + bbase + n * 2048 + swz0);
                    bf[n][1] = *(const i32x4*)(buf + bbase + n * 2048 + swz1);
                }
            }
            i32x4 af0_0 = *(const i32x4*)(buf + abase + (2 * p) * 2048 + swz0);
            i32x4 af0_1 = *(const i32x4*)(buf + abase + (2 * p) * 2048 + swz1);
            i32x4 af1_0 = *(const i32x4*)(buf + abase + (2 * p + 1) * 2048 + swz0);
            i32x4 af1_1 = *(const i32x4*)(buf + abase + (2 * p + 1) * 2048 + swz1);
            // --- stage next K-tile: A halves at P0, B halves at P1 ---
            if (p == 0 && more) {
                #pragma unroll
                for (int i = 0; i < 4; ++i)
                    async16(gA + (size_t)(i * 64) * K + koff, nbuf + i * 8192 + dst_t);
            }
            if (p == 1 && more) {
                #pragma unroll
                for (int i = 0; i < 4; ++i)
                    async16(gB + (size_t)(i * 64) * K + koff, nbuf + 32768 + i * 8192 + dst_t);
            }
            __builtin_amdgcn_s_barrier();
            asm volatile("s_waitcnt lgkmcnt(0)" ::: "memory");
            __builtin_amdgcn_sched_barrier(0);
            __builtin_amdgcn_s_setprio(1);
            #pragma unroll
            for (int n = 0; n < 4; ++n) {
                acc[2 * p][n]     = __builtin_amdgcn_mfma_i32_16x16x64_i8(af0_0, bf[n][0], acc[2 * p][n], 0, 0, 0);
                acc[2 * p][n]     = __builtin_amdgcn_mfma_i32_16x16x64_i8(af0_1, bf[n][1], acc[2 * p][n], 0, 0, 0);
                acc[2 * p + 1][n] = __builtin_amdgcn_mfma_i32_16x16x64_i8(af1_0, bf[n][0], acc[2 * p + 1][n], 0, 0, 0);
                acc[2 * p + 1][n] = __builtin_amdgcn_mfma_i32_16x16x64_i8(af1_1, bf[n][1], acc[2 * p + 1][n], 0, 0, 0);
            }
            __builtin_amdgcn_s_setprio(0);
            if (p == 3) {
                // next tile's staged loads must be LDS-resident before any wave
                // crosses the following barrier (reads start right after it)
                asm volatile("s_waitcnt vmcnt(0)" ::: "memory");
            }
            __builtin_amdgcn_s_barrier();
        }
    }

    // ---- epilogue: lin = acc + z*rowsum + round(fp_bias/(ws*xs)); track max|lin| ----
    const float ws = *w_scale_p;
    const int rowg0 = tm * 256 + wm * 128 + lane_hi * 4;   // + m*16 + r
    const int colg0 = tn * 256 + wn * 64 + lane_lo;        // + n*16
    float fb[4]; int wrs[4];
    #pragma unroll
    for (int n = 0; n < 4; ++n) {
        fb[n] = fp_bias[colg0 + n * 16];
        wrs[n] = w_rowsum[colg0 + n * 16];
    }
    int lmax = 0;
    #pragma unroll
    for (int m = 0; m < 8; ++m) {
        #pragma unroll
        for (int r = 0; r < 4; ++r) {
            const int row = rowg0 + m * 16 + r;
            const float xs = x_scale[row];
            const int zz = 128 - (int)x_zp[row];
            const float d = ws * xs;
            int* orow = lin_out + (size_t)row * N + colg0;
            #pragma unroll
            for (int n = 0; n < 4; ++n) {
                const int qb = (int)rintf(fb[n] / d);
                const int lin = acc[m][n][r] + zz * wrs[n] + qb;
                const int a = lin < 0 ? -lin : lin;
                lmax = a > lmax ? a : lmax;
                orow[n * 16] = lin;
            }
        }
    }
    atomicMax(&s_bmax, lmax);
    __syncthreads();
    if (t == 0) atomicMax(gmax, s_bmax);
}

// ---- pass 3: requantize in place (int32 lin -> float q) ----
__global__ void requant_kernel(float4* qout, const int4* lin, const int* gmax, int n4) {
    int i = blockIdx.x * 256 + threadIdx.x;
    if (i >= n4) return;
    float s = (float)(*gmax) / 127.0f;
    int4 v = lin[i];
    float4 o;
    o.x = fminf(127.0f, fmaxf(-127.0f, rintf((float)v.x / s)));
    o.y = fminf(127.0f, fmaxf(-127.0f, rintf((float)v.y / s)));
    o.z = fminf(127.0f, fmaxf(-127.0f, rintf((float)v.z / s)));
    o.w = fminf(127.0f, fmaxf(-127.0f, rintf((float)v.w / s)));
    qout[i] = o;
}

// ---- pass 4: out_scale[b] = s * x_scale[b] * w_scale; zero_point = 0 ----
__global__ void scale_kernel(float* __restrict__ out_scale, float* __restrict__ out_zp,
                             const float* __restrict__ x_scale,
                             const float* __restrict__ w_scale_p,
                             const int* gmax, int B) {
    int i = blockIdx.x * 256 + threadIdx.x;
    if (i >= B) return;
    float s = (float)(*gmax) / 127.0f;
    out_scale[i] = s * x_scale[i] * w_scale_p[0];
    out_zp[i] = 0.0f;
}

extern "C" void kernel_launch(void* const* d_in, const int* in_sizes, int n_in,
                              void* d_out, int out_size, void* d_ws, size_t ws_size,
                              hipStream_t stream) {
    const float* x_q     = (const float*)d_in[0];
    const float* x_scale = (const float*)d_in[1];
    const float* x_zp    = (const float*)d_in[2];
    const float* w_q     = (const float*)d_in[3];
    const float* w_scale = (const float*)d_in[4];
    const float* fp_bias = (const float*)d_in[5];

    const int B   = in_sizes[1];           // 8192
    const int IN  = in_sizes[0] / B;       // 4096
    const int OUT = in_sizes[5];           // 4096

    float* q         = (float*)d_out;
    float* out_scale = q + (size_t)B * OUT;
    float* out_zp    = out_scale + B;

    // workspace layout
    char* ws    = (char*)d_ws;
    int* gmax   = (int*)ws;
    char* x8    = ws + 64;
    char* w8    = x8 + (size_t)B * IN;
    int* rowsum = (int*)(w8 + (size_t)OUT * IN);
    size_t needed = 64 + (size_t)B * IN + (size_t)OUT * IN + (size_t)OUT * 4;
    if (ws_size < needed) return;  // would corrupt; fail loudly with zero output

    int n4x = (B * IN) >> 2;
    conv_x_kernel<<<(n4x + 255) / 256, 256, 0, stream>>>((const float4*)x_q, (int*)x8, gmax, n4x);
    conv_w_kernel<<<OUT, 256, 0, stream>>>(w_q, (int*)w8, rowsum, IN);

    int nblocks = (B / 256) * (OUT / 256);   // 512
    gemm_i8_kernel<<<nblocks, 512, 0, stream>>>(x8, w8, rowsum, x_scale, x_zp, fp_bias,
                                                w_scale, (int*)q, gmax, OUT, IN);

    int n4q = (B * OUT) >> 2;
    requant_kernel<<<(n4q + 255) / 256, 256, 0, stream>>>((float4*)q, (const int4*)q, gmax, n4q);
    scale_kernel<<<(B + 255) / 256, 256, 0, stream>>>(out_scale, out_zp, x_scale, w_scale, gmax, B);
}